// Round 7
// baseline (475.160 us; speedup 1.0000x reference)
//
#include <hip/hip_runtime.h>
#include <math.h>

#define NN 50000
#define NE 800000
#define FIN 500
#define NCLS 40
#define NB 196  // scan blocks = ceil(NN/256)

typedef short short8 __attribute__((ext_vector_type(8)));
typedef float f32x4 __attribute__((ext_vector_type(4)));

__device__ __forceinline__ unsigned short f2bf(float f) {
    unsigned u = __float_as_uint(f);
    unsigned r = (u + 0x7FFFu + ((u >> 16) & 1u)) >> 16;
    return (unsigned short)r;
}
__device__ __forceinline__ float bf2f(unsigned short h) {
    return __uint_as_float(((unsigned)h) << 16);
}

// global -> LDS direct copy, 16B per lane; LDS dest is wave-uniform base + lane*16
typedef const __attribute__((address_space(1))) void gv1;
typedef __attribute__((address_space(3))) void lv3;
__device__ __forceinline__ void gl16(const void* g, void* l) {
    __builtin_amdgcn_global_load_lds((gv1*)g, (lv3*)l, 16, 0, 0);
}

// ---- weight split+transpose into blocked, pre-swizzled layout ----
// dst layout: [yb][ck64][r (0..BN-1)][16 x 16B-chunks: hi 0-7, lo 8-15, chunk^ (r&7)]
__global__ void k_wsplit(const float* __restrict__ W, short* __restrict__ dst,
                         int Ksrc, int Ncols, int Kpad, int BN, int koff,
                         int noff, int llog) {
    int i = blockIdx.x * 256 + threadIdx.x;
    int len = 1 << llog;
    if (i >= Ncols * len) return;
    int n = i >> llog, kk = i & (len - 1);
    float v = (kk < Ksrc) ? W[(size_t)kk * Ncols + n] : 0.f;
    unsigned short hi = f2bf(v);
    float lo = v - bf2f(hi);
    int nd = noff + n, kd = koff + kk;
    int yb = nd / BN, r = nd % BN;
    int ck = kd >> 6, kin = kd & 63;
    int c16h = (kin >> 3) ^ (r & 7);
    size_t rowb = (((size_t)yb * (Kpad >> 6) + ck) * BN + r) * 128;
    dst[rowb + c16h * 8 + (kin & 7)] = (short)hi;
    dst[rowb + (8 + c16h) * 8 + (kin & 7)] = (short)f2bf(lo);
}

// ---------------- counting sort of edges by dst ----------------
__global__ void k_count(const int* __restrict__ dst, int* __restrict__ deg) {
    int e = blockIdx.x * blockDim.x + threadIdx.x;
    if (e < NE) atomicAdd(&deg[dst[e]], 1);
}

__global__ void k_scan1(const int* __restrict__ deg, int* __restrict__ offs,
                        int* __restrict__ bsum) {
    __shared__ int sm[256];
    int tid = threadIdx.x;
    int i = blockIdx.x * 256 + tid;
    int v = (i < NN) ? deg[i] : 0;
    sm[tid] = v;
    __syncthreads();
    for (int off = 1; off < 256; off <<= 1) {
        int t = (tid >= off) ? sm[tid - off] : 0;
        __syncthreads();
        sm[tid] += t;
        __syncthreads();
    }
    if (i < NN) offs[i] = sm[tid] - v;
    if (tid == 255) bsum[blockIdx.x] = sm[255];
}

__global__ void k_scan2(const int* __restrict__ bsum, int* __restrict__ bpre,
                        int* __restrict__ offs) {
    __shared__ int sm[256];
    int tid = threadIdx.x;
    int v = (tid < NB) ? bsum[tid] : 0;
    sm[tid] = v;
    __syncthreads();
    for (int off = 1; off < 256; off <<= 1) {
        int t = (tid >= off) ? sm[tid - off] : 0;
        __syncthreads();
        sm[tid] += t;
        __syncthreads();
    }
    if (tid < NB) bpre[tid] = sm[tid] - v;
    if (tid == 255) offs[NN] = sm[255];
}

__global__ void k_scan3(int* __restrict__ offs, const int* __restrict__ bpre,
                        int* __restrict__ cursor) {
    int i = blockIdx.x * 256 + threadIdx.x;
    if (i < NN) {
        int v = offs[i] + bpre[blockIdx.x];
        offs[i] = v;
        cursor[i] = v;
    }
}

__global__ void k_scatter(const int* __restrict__ src, const int* __restrict__ dst,
                          int* __restrict__ cursor, int* __restrict__ ssrc) {
    int e = blockIdx.x * blockDim.x + threadIdx.x;
    if (e < NE) {
        int p = atomicAdd(&cursor[dst[e]], 1);
        ssrc[p] = src[e];
    }
}

// ---- mean aggregation from bf16 table [NN][128] -> bf16 mean plane [NN][128] ----
// one wave per node; 16-lane subwave per edge (16B/lane); 4 edges/subwave in flight
__global__ __launch_bounds__(256) void k_aggb(
    const short* __restrict__ hb, const int* __restrict__ offs,
    const int* __restrict__ ssrc, short* __restrict__ mH) {
    int wid = (blockIdx.x * 256 + threadIdx.x) >> 6;
    int lane = threadIdx.x & 63;
    if (wid >= NN) return;
    int sub = lane >> 4, l16 = lane & 15;
    int beg = offs[wid], end = offs[wid + 1];
    f32x4 a0 = {0.f, 0.f, 0.f, 0.f}, a1 = {0.f, 0.f, 0.f, 0.f};
    int i = beg + sub;
    for (; i + 12 < end; i += 16) {
        int s0 = ssrc[i];
        int s1 = ssrc[i + 4];
        int s2 = ssrc[i + 8];
        int s3 = ssrc[i + 12];
        short8 v0 = *(const short8*)(hb + (size_t)s0 * 128 + l16 * 8);
        short8 v1 = *(const short8*)(hb + (size_t)s1 * 128 + l16 * 8);
        short8 v2 = *(const short8*)(hb + (size_t)s2 * 128 + l16 * 8);
        short8 v3 = *(const short8*)(hb + (size_t)s3 * 128 + l16 * 8);
#pragma unroll
        for (int j = 0; j < 4; ++j) {
            a0[j] += (bf2f((unsigned short)v0[j]) + bf2f((unsigned short)v1[j])) +
                     (bf2f((unsigned short)v2[j]) + bf2f((unsigned short)v3[j]));
            a1[j] += (bf2f((unsigned short)v0[j + 4]) + bf2f((unsigned short)v1[j + 4])) +
                     (bf2f((unsigned short)v2[j + 4]) + bf2f((unsigned short)v3[j + 4]));
        }
    }
    for (; i < end; i += 4) {
        int s0 = ssrc[i];
        short8 v0 = *(const short8*)(hb + (size_t)s0 * 128 + l16 * 8);
#pragma unroll
        for (int j = 0; j < 4; ++j) {
            a0[j] += bf2f((unsigned short)v0[j]);
            a1[j] += bf2f((unsigned short)v0[j + 4]);
        }
    }
#pragma unroll
    for (int j = 0; j < 4; ++j) {
        a0[j] += __shfl_xor(a0[j], 16);
        a0[j] += __shfl_xor(a0[j], 32);
        a1[j] += __shfl_xor(a1[j], 16);
        a1[j] += __shfl_xor(a1[j], 32);
    }
    if (sub == 0) {
        float inv = 1.f / fmaxf((float)(end - beg), 1.f);
        a0 *= inv; a1 *= inv;
        short8 hv;
#pragma unroll
        for (int j = 0; j < 4; ++j) {
            hv[j] = (short)f2bf(a0[j]);
            hv[j + 4] = (short)f2bf(a1[j]);
        }
        *(short8*)(mH + (size_t)wid * 128 + l16 * 8) = hv;
    }
}

// ---------------- MFMA GEMM: A direct-to-reg, B global_load_lds double-buffered ----------------
// 512 threads = 8 waves; wave w owns rows [bx*128 + w*16, +16) x BN cols (colBase = by*BN).
// B slab per (yb, ck64): BN rows x 128 shorts (8 hi + 8 lo 16B-chunks, XOR-swizzled).
// BN=64: slab 16KB, dbuf 32KB -> 4 blocks/CU (LDS 128KB, 2048 thr) = 32 waves/CU;
// grid 782-1564 blocks (3-6/CU) so queued blocks fill barrier-drain stalls (m97 regime).
// PQ epilogue: cols [0,splitN) -> CH as bf16 (ldc-padded); cols [splitN,N) -> F0 fp32.
template <int BN, int KPAD, int KS0, int KREAL, bool AFP32, bool RELU, bool PQ>
__global__ __launch_bounds__(512, 8) void k_mm6(
    const void* __restrict__ A0v, const short* __restrict__ A1,
    const short* __restrict__ Bg, const float* __restrict__ bias,
    short* __restrict__ CH, int ldc,
    float* __restrict__ F0, float* __restrict__ F1, int splitN,
    int M, int N) {
    constexpr int NT = BN / 16;      // col tiles per wave
    constexpr int C = KPAD / 64;     // 64-wide k-chunks
    constexpr int PT = (BN * 16) / 512;  // gload_lds issues per thread per chunk
    constexpr int SLAB = BN * 128;   // shorts per buffer
    static_assert((BN * 16) % 512 == 0, "staging divisibility");
    __shared__ short Bs[2 * SLAB];
    int tid = threadIdx.x;
    int wave = tid >> 6, lane = tid & 63;
    int quad = lane >> 4, l16 = lane & 15;
    int colBase = blockIdx.y * BN;
    int r0 = blockIdx.x * 128 + wave * 16 + l16;
    int r0c = min(r0, M - 1);
    const short* Bbase = Bg + (size_t)blockIdx.y * (C * SLAB);

    f32x4 acc[NT];
#pragma unroll
    for (int n = 0; n < NT; ++n) acc[n] = (f32x4){0.f, 0.f, 0.f, 0.f};

    auto stageB = [&](int buf, int ck) {
        const short* src = Bbase + (size_t)ck * SLAB;
        short* db = Bs + buf * SLAB;
#pragma unroll
        for (int u = 0; u < PT; ++u) {
            int base = u * 512 + wave * 64;                 // wave-uniform chunk base
            gl16(src + (size_t)(base + lane) * 8, db + (size_t)base * 8);
        }
    };

    short8 aPre[AFP32 ? 2 : (2 * C)];  // bf16: all frags; fp32: unused slot count kept tiny
    short8 aCur[2];
    f32x4 fN[4];
    const float* Af = (const float*)A0v + (size_t)r0c * (size_t)KREAL;

    auto ldA32 = [&](int ck) {
#pragma unroll
        for (int s = 0; s < 2; ++s) {
            int kg = ck * 64 + s * 32 + quad * 8;
            f32x4 f0 = {0.f, 0.f, 0.f, 0.f}, f1 = {0.f, 0.f, 0.f, 0.f};
            if (kg < KREAL) f0 = *(const f32x4*)(Af + kg);
            if (kg + 4 < KREAL) f1 = *(const f32x4*)(Af + kg + 4);
            fN[s * 2] = f0;
            fN[s * 2 + 1] = f1;
        }
    };
    auto cvtA = [&]() {
#pragma unroll
        for (int s = 0; s < 2; ++s) {
            short8 a;
#pragma unroll
            for (int j = 0; j < 4; ++j) {
                a[j] = (short)f2bf(fN[s * 2][j]);
                a[j + 4] = (short)f2bf(fN[s * 2 + 1][j]);
            }
            aCur[s] = a;
        }
    };

    if constexpr (!AFP32) {
        const short* A0 = (const short*)A0v;
#pragma unroll
        for (int c = 0; c < C; ++c) {
            const bool seg = (c * 64 >= KS0);
            const short* ap = seg ? A1 : A0;
            const int w = seg ? (KPAD - KS0) : KS0;
            const int col = c * 64 - (seg ? KS0 : 0);
#pragma unroll
            for (int s = 0; s < 2; ++s)
                aPre[c * 2 + s] =
                    *(const short8*)(ap + (size_t)r0c * w + col + s * 32 + quad * 8);
        }
    } else {
        ldA32(0);
        cvtA();
    }

    stageB(0, 0);
    __syncthreads();   // chunk 0 staged (drains vmcnt incl. gload_lds on all waves)

#pragma unroll
    for (int ck = 0; ck < C; ++ck) {
        if (ck + 1 < C) {
            stageB((ck + 1) & 1, ck + 1);     // async into the other buffer
            if constexpr (AFP32) ldA32(ck + 1);
        }
        const short* bb = Bs + (ck & 1) * SLAB;
#pragma unroll
        for (int s = 0; s < 2; ++s) {
            short8 a;
            if constexpr (AFP32) a = aCur[s];
            else                 a = aPre[ck * 2 + s];
#pragma unroll
            for (int n = 0; n < NT; ++n) {
                int r = n * 16 + l16;
                int ch = (s * 4 + quad) ^ (r & 7);
                short8 bh = *(const short8*)(bb + r * 128 + ch * 8);
                short8 bl = *(const short8*)(bb + r * 128 + (8 + ch) * 8);
                acc[n] = __builtin_amdgcn_mfma_f32_16x16x32_bf16(a, bh, acc[n], 0, 0, 0);
                acc[n] = __builtin_amdgcn_mfma_f32_16x16x32_bf16(a, bl, acc[n], 0, 0, 0);
            }
        }
        if (ck + 1 < C) {
            __syncthreads();                  // next chunk staged & all reads of this buf done
            if constexpr (AFP32) cvtA();
        }
    }

    // ---- epilogue: C-layout col=lane&15, row=quad*4+reg ----
    int gr0 = blockIdx.x * 128 + wave * 16 + quad * 4;
#pragma unroll
    for (int n = 0; n < NT; ++n) {
        int gc = colBase + n * 16 + l16;
        if (gc >= N) continue;
        float b = bias ? bias[gc] : 0.f;
#pragma unroll
        for (int r = 0; r < 4; ++r) {
            int gr = gr0 + r;
            if (gr < M) {
                float v = acc[n][r] + b;
                if (RELU) v = fmaxf(v, 0.f);
                if constexpr (PQ) {
                    if (gc < splitN) CH[(size_t)gr * ldc + gc] = (short)f2bf(v);
                    else             F0[(size_t)gr * (N - splitN) + (gc - splitN)] = v;
                } else {
                    if (CH) CH[(size_t)gr * ldc + gc] = (short)f2bf(v);
                    if (F0) {
                        if (gc < splitN) F0[(size_t)gr * splitN + gc] = v;
                        else             F1[(size_t)gr * (N - splitN) + (gc - splitN)] = v;
                    }
                }
            }
        }
    }
}

// ---------------- fused layer-3 aggregation + bias + residual + log_softmax ----------------
// pH: bf16 [NN][64] (cols 0-39 valid, rows 128B-aligned); q: fp32 [NN][40]
// 4-deep unrolled gather for MLP.
__global__ __launch_bounds__(256) void k_final(
    const short* __restrict__ pH, const float* __restrict__ q,
    const int* __restrict__ offs, const int* __restrict__ ssrc,
    const float* __restrict__ bl3, float* __restrict__ out) {
    int wid = (blockIdx.x * 256 + threadIdx.x) >> 6;
    int lane = threadIdx.x & 63;
    if (wid >= NN) return;
    bool act = lane < NCLS;
    int beg = offs[wid], end = offs[wid + 1];
    float a0 = 0.f, a1 = 0.f, a2 = 0.f, a3 = 0.f;
    int i = beg;
    for (; i + 3 < end; i += 4) {
        int s0 = ssrc[i], s1 = ssrc[i + 1], s2 = ssrc[i + 2], s3 = ssrc[i + 3];
        if (act) {
            a0 += bf2f((unsigned short)pH[(size_t)s0 * 64 + lane]);
            a1 += bf2f((unsigned short)pH[(size_t)s1 * 64 + lane]);
            a2 += bf2f((unsigned short)pH[(size_t)s2 * 64 + lane]);
            a3 += bf2f((unsigned short)pH[(size_t)s3 * 64 + lane]);
        }
    }
    for (; i < end; ++i) {
        int s0 = ssrc[i];
        if (act) a0 += bf2f((unsigned short)pH[(size_t)s0 * 64 + lane]);
    }
    float inv = 1.f / fmaxf((float)(end - beg), 1.f);
    float v = act ? ((a0 + a1) + (a2 + a3)) * inv + bl3[lane] + q[(size_t)wid * NCLS + lane]
                  : -INFINITY;
    float m = v;
#pragma unroll
    for (int off = 32; off > 0; off >>= 1) m = fmaxf(m, __shfl_xor(m, off));
    float e = act ? expf(v - m) : 0.f;
    float s = e;
#pragma unroll
    for (int off = 32; off > 0; off >>= 1) s += __shfl_xor(s, off);
    float ls = logf(s);
    if (act) out[(size_t)wid * NCLS + lane] = v - m - ls;
}

extern "C" void kernel_launch(void* const* d_in, const int* in_sizes, int n_in,
                              void* d_out, int out_size, void* d_ws, size_t ws_size,
                              hipStream_t stream) {
    const float* x    = (const float*)d_in[0];
    const int*   ei   = (const int*)d_in[1];
    const int*   esrc = ei;        // row 0: src
    const int*   edst = ei + NE;   // row 1: dst
    const float* W_map = (const float*)d_in[2];
    const float* b_map = (const float*)d_in[3];
    const float* Wl1   = (const float*)d_in[4];
    const float* bl1   = (const float*)d_in[5];
    const float* Wr1   = (const float*)d_in[6];
    const float* Wl2   = (const float*)d_in[7];
    const float* bl2   = (const float*)d_in[8];
    const float* Wr2   = (const float*)d_in[9];
    const float* Wl3   = (const float*)d_in[10];
    const float* bl3   = (const float*)d_in[11];
    const float* Wr3   = (const float*)d_in[12];
    float* out = (float*)d_out;

    char* ws = (char*)d_ws;
    short* h0H = (short*)ws; ws += (size_t)NN * 128 * 2;
    short* m0H = (short*)ws; ws += (size_t)NN * 128 * 2;
    short* h1H = (short*)ws; ws += (size_t)NN * 128 * 2;
    short* m1H = (short*)ws; ws += (size_t)NN * 128 * 2;
    short* h2H = (short*)ws; ws += (size_t)NN * 256 * 2;
    short* pH  = (short*)ws; ws += (size_t)NN * 64 * 2;   // bf16, rows padded to 64
    float* q   = (float*)ws; ws += (size_t)NN * NCLS * 4;
    short* wt  = (short*)ws; ws += (size_t)376832 * 2;
    int* deg    = (int*)ws;  ws += (size_t)NN * 4;
    int* offs   = (int*)ws;  ws += (size_t)(NN + 2) * 4;
    int* cursor = (int*)ws;  ws += (size_t)NN * 4;
    int* ssrc   = (int*)ws;  ws += (size_t)NE * 4;
    int* bsum   = (int*)ws;  ws += (size_t)256 * 4;
    int* bpre   = (int*)ws;  ws += (size_t)256 * 4;

    // blocked pre-swizzled weight buffers: [yb][ck64][BN][128], BN=64 (b3w: 96)
    short* m_w  = wt + 0;       // 2yb * 8ck * 64 * 128 = 131072
    short* b1w  = wt + 131072;  // 2yb * 4ck * 64 * 128 = 65536
    short* b2w  = wt + 196608;  // 4yb * 4ck * 64 * 128 = 131072
    short* b3w  = wt + 327680;  // 1yb * 4ck * 96 * 128 = 49152  (total 376832)

    // --- weight split/transpose (tiny) ---
    (void)hipMemsetAsync(b3w, 0, (size_t)49152 * 2, stream);  // zero pad rows 80-95
    k_wsplit<<<(128 * 512 + 255) / 256, 256, 0, stream>>>(W_map, m_w, FIN, 128, 512, 64, 0, 0, 9);
    k_wsplit<<<(128 * 128 + 255) / 256, 256, 0, stream>>>(Wr1, b1w, 128, 128, 256, 64, 0, 0, 7);
    k_wsplit<<<(128 * 128 + 255) / 256, 256, 0, stream>>>(Wl1, b1w, 128, 128, 256, 64, 128, 0, 7);
    k_wsplit<<<(256 * 128 + 255) / 256, 256, 0, stream>>>(Wr2, b2w, 128, 256, 256, 64, 0, 0, 7);
    k_wsplit<<<(256 * 128 + 255) / 256, 256, 0, stream>>>(Wl2, b2w, 128, 256, 256, 64, 128, 0, 7);
    k_wsplit<<<(40 * 256 + 255) / 256, 256, 0, stream>>>(Wl3, b3w, 256, 40, 256, 96, 0, 0, 8);
    k_wsplit<<<(40 * 256 + 255) / 256, 256, 0, stream>>>(Wr3, b3w, 256, 40, 256, 96, 0, 40, 8);

    // --- CSR bucketing of edges by dst (two-level scan) ---
    (void)hipMemsetAsync(deg, 0, (size_t)NN * 4, stream);
    k_count<<<(NE + 255) / 256, 256, 0, stream>>>(edst, deg);
    k_scan1<<<NB, 256, 0, stream>>>(deg, offs, bsum);
    k_scan2<<<1, 256, 0, stream>>>(bsum, bpre, offs);
    k_scan3<<<NB, 256, 0, stream>>>(offs, bpre, cursor);
    k_scatter<<<(NE + 255) / 256, 256, 0, stream>>>(esrc, edst, cursor, ssrc);

    const int g128 = (NN + 127) / 128;  // 391
    const int aggBlocks = (NN * 64) / 256;

    // h0 = x @ W_map + b_map -> h0H [NN][128] bf16
    k_mm6<64, 512, 512, FIN, true, false, false><<<dim3(g128, 2), 512, 0, stream>>>(
        (const void*)x, nullptr, m_w, b_map,
        h0H, 128, nullptr, nullptr, 0, NN, 128);

    // mean(h0) -> m0H
    k_aggb<<<aggBlocks, 256, 0, stream>>>(h0H, offs, ssrc, m0H);

    // h1 = relu([h0|mean] @ [Wr1;Wl1] + bl1) -> h1H
    k_mm6<64, 256, 128, 256, false, true, false><<<dim3(g128, 2), 512, 0, stream>>>(
        (const void*)h0H, m0H, b1w, bl1,
        h1H, 128, nullptr, nullptr, 0, NN, 128);

    // mean(h1) -> m1H
    k_aggb<<<aggBlocks, 256, 0, stream>>>(h1H, offs, ssrc, m1H);

    // h2 = relu([h1|mean] @ [Wr2;Wl2] + bl2) -> h2H [NN][256]
    k_mm6<64, 256, 128, 256, false, true, false><<<dim3(g128, 4), 512, 0, stream>>>(
        (const void*)h1H, m1H, b2w, bl2,
        h2H, 256, nullptr, nullptr, 0, NN, 256);

    // [p|q] = h2 @ [Wl3|Wr3] (BN padded to 96): cols 0-39 -> pH (bf16, ldc=64), 40-79 -> q
    k_mm6<96, 256, 256, 256, false, false, true><<<dim3(g128, 1), 512, 0, stream>>>(
        (const void*)h2H, nullptr, b3w, nullptr,
        pH, 64, q, nullptr, NCLS, NN, 80);

    // fused: logits = mean_agg(pH) + bl3 + q; log_softmax -> out
    k_final<<<aggBlocks, 256, 0, stream>>>(pH, q, offs, ssrc, bl3, out);
}

// Round 9
// 462.090 us; speedup vs baseline: 1.0283x; 1.0283x over previous
//
#include <hip/hip_runtime.h>
#include <math.h>

#define NN 50000
#define NE 800000
#define FIN 500
#define NCLS 40
#define NB 196  // scan blocks = ceil(NN/256)

typedef short short8 __attribute__((ext_vector_type(8)));
typedef float f32x4 __attribute__((ext_vector_type(4)));

__device__ __forceinline__ unsigned short f2bf(float f) {
    unsigned u = __float_as_uint(f);
    unsigned r = (u + 0x7FFFu + ((u >> 16) & 1u)) >> 16;
    return (unsigned short)r;
}
__device__ __forceinline__ float bf2f(unsigned short h) {
    return __uint_as_float(((unsigned)h) << 16);
}

// global -> LDS direct copy, 16B per lane; LDS dest is wave-uniform base + lane*16
typedef const __attribute__((address_space(1))) void gv1;
typedef __attribute__((address_space(3))) void lv3;
__device__ __forceinline__ void gl16(const void* g, void* l) {
    __builtin_amdgcn_global_load_lds((gv1*)g, (lv3*)l, 16, 0, 0);
}

// ---- weight split+transpose into blocked, pre-swizzled layout ----
// dst layout: [yb][ck64][r (0..BN-1)][16 x 16B-chunks: hi 0-7, lo 8-15, chunk^ (r&7)]
__global__ void k_wsplit(const float* __restrict__ W, short* __restrict__ dst,
                         int Ksrc, int Ncols, int Kpad, int BN, int koff,
                         int noff, int llog) {
    int i = blockIdx.x * 256 + threadIdx.x;
    int len = 1 << llog;
    if (i >= Ncols * len) return;
    int n = i >> llog, kk = i & (len - 1);
    float v = (kk < Ksrc) ? W[(size_t)kk * Ncols + n] : 0.f;
    unsigned short hi = f2bf(v);
    float lo = v - bf2f(hi);
    int nd = noff + n, kd = koff + kk;
    int yb = nd / BN, r = nd % BN;
    int ck = kd >> 6, kin = kd & 63;
    int c16h = (kin >> 3) ^ (r & 7);
    size_t rowb = (((size_t)yb * (Kpad >> 6) + ck) * BN + r) * 128;
    dst[rowb + c16h * 8 + (kin & 7)] = (short)hi;
    dst[rowb + (8 + c16h) * 8 + (kin & 7)] = (short)f2bf(lo);
}

// ---------------- counting sort of edges by dst ----------------
__global__ void k_count(const int* __restrict__ dst, int* __restrict__ deg) {
    int e = blockIdx.x * blockDim.x + threadIdx.x;
    if (e < NE) atomicAdd(&deg[dst[e]], 1);
}

__global__ void k_scan1(const int* __restrict__ deg, int* __restrict__ offs,
                        int* __restrict__ bsum) {
    __shared__ int sm[256];
    int tid = threadIdx.x;
    int i = blockIdx.x * 256 + tid;
    int v = (i < NN) ? deg[i] : 0;
    sm[tid] = v;
    __syncthreads();
    for (int off = 1; off < 256; off <<= 1) {
        int t = (tid >= off) ? sm[tid - off] : 0;
        __syncthreads();
        sm[tid] += t;
        __syncthreads();
    }
    if (i < NN) offs[i] = sm[tid] - v;
    if (tid == 255) bsum[blockIdx.x] = sm[255];
}

__global__ void k_scan2(const int* __restrict__ bsum, int* __restrict__ bpre,
                        int* __restrict__ offs) {
    __shared__ int sm[256];
    int tid = threadIdx.x;
    int v = (tid < NB) ? bsum[tid] : 0;
    sm[tid] = v;
    __syncthreads();
    for (int off = 1; off < 256; off <<= 1) {
        int t = (tid >= off) ? sm[tid - off] : 0;
        __syncthreads();
        sm[tid] += t;
        __syncthreads();
    }
    if (tid < NB) bpre[tid] = sm[tid] - v;
    if (tid == 255) offs[NN] = sm[255];
}

__global__ void k_scan3(int* __restrict__ offs, const int* __restrict__ bpre,
                        int* __restrict__ cursor) {
    int i = blockIdx.x * 256 + threadIdx.x;
    if (i < NN) {
        int v = offs[i] + bpre[blockIdx.x];
        offs[i] = v;
        cursor[i] = v;
    }
}

__global__ void k_scatter(const int* __restrict__ src, const int* __restrict__ dst,
                          int* __restrict__ cursor, int* __restrict__ ssrc) {
    int e = blockIdx.x * blockDim.x + threadIdx.x;
    if (e < NE) {
        int p = atomicAdd(&cursor[dst[e]], 1);
        ssrc[p] = src[e];
    }
}

// ---- mean aggregation from bf16 table [NN][128] -> bf16 mean plane [NN][128] ----
// one wave per node; 16-lane subwave per edge (16B/lane); 4 edges/subwave in flight
__global__ __launch_bounds__(256) void k_aggb(
    const short* __restrict__ hb, const int* __restrict__ offs,
    const int* __restrict__ ssrc, short* __restrict__ mH) {
    int wid = (blockIdx.x * 256 + threadIdx.x) >> 6;
    int lane = threadIdx.x & 63;
    if (wid >= NN) return;
    int sub = lane >> 4, l16 = lane & 15;
    int beg = offs[wid], end = offs[wid + 1];
    f32x4 a0 = {0.f, 0.f, 0.f, 0.f}, a1 = {0.f, 0.f, 0.f, 0.f};
    int i = beg + sub;
    for (; i + 12 < end; i += 16) {
        int s0 = ssrc[i];
        int s1 = ssrc[i + 4];
        int s2 = ssrc[i + 8];
        int s3 = ssrc[i + 12];
        short8 v0 = *(const short8*)(hb + (size_t)s0 * 128 + l16 * 8);
        short8 v1 = *(const short8*)(hb + (size_t)s1 * 128 + l16 * 8);
        short8 v2 = *(const short8*)(hb + (size_t)s2 * 128 + l16 * 8);
        short8 v3 = *(const short8*)(hb + (size_t)s3 * 128 + l16 * 8);
#pragma unroll
        for (int j = 0; j < 4; ++j) {
            a0[j] += (bf2f((unsigned short)v0[j]) + bf2f((unsigned short)v1[j])) +
                     (bf2f((unsigned short)v2[j]) + bf2f((unsigned short)v3[j]));
            a1[j] += (bf2f((unsigned short)v0[j + 4]) + bf2f((unsigned short)v1[j + 4])) +
                     (bf2f((unsigned short)v2[j + 4]) + bf2f((unsigned short)v3[j + 4]));
        }
    }
    for (; i < end; i += 4) {
        int s0 = ssrc[i];
        short8 v0 = *(const short8*)(hb + (size_t)s0 * 128 + l16 * 8);
#pragma unroll
        for (int j = 0; j < 4; ++j) {
            a0[j] += bf2f((unsigned short)v0[j]);
            a1[j] += bf2f((unsigned short)v0[j + 4]);
        }
    }
#pragma unroll
    for (int j = 0; j < 4; ++j) {
        a0[j] += __shfl_xor(a0[j], 16);
        a0[j] += __shfl_xor(a0[j], 32);
        a1[j] += __shfl_xor(a1[j], 16);
        a1[j] += __shfl_xor(a1[j], 32);
    }
    if (sub == 0) {
        float inv = 1.f / fmaxf((float)(end - beg), 1.f);
        a0 *= inv; a1 *= inv;
        short8 hv;
#pragma unroll
        for (int j = 0; j < 4; ++j) {
            hv[j] = (short)f2bf(a0[j]);
            hv[j + 4] = (short)f2bf(a1[j]);
        }
        *(short8*)(mH + (size_t)wid * 128 + l16 * 8) = hv;
    }
}

// ---------------- MFMA GEMM: counted-vmcnt pipeline, race-free ordering ----------------
// 512 threads = 8 waves; wave w owns rows [bx*128 + w*16, +16) x BN cols.
// Per iteration ck:
//   s_waitcnt vmcnt(W)   // W = loads issued after stage(ck): own stage(ck)[+A(ck)] done
//   s_barrier            // => all waves' stage(ck) visible AND compute(ck-1) reads consumed
//   stage(ck+1)          // safe to overwrite buf[(ck+1)&1] only after that barrier
//   cvtA / ldA(ck+2)
//   compute(ck)
// vmcnt FIFO: oldest complete first, so W=NA leaves only A(ck+1) in flight.
template <int BN, int KPAD, int KS0, int KREAL, bool AFP32, bool RELU, bool PQ>
__global__ __launch_bounds__(512, 4) void k_mm8(
    const void* __restrict__ A0v, const short* __restrict__ A1,
    const short* __restrict__ Bg, const float* __restrict__ bias,
    short* __restrict__ CH, int ldc,
    float* __restrict__ F0, float* __restrict__ F1, int splitN,
    int M, int N) {
    constexpr int NT = BN / 16;          // col tiles per wave
    constexpr int C = KPAD / 64;         // 64-wide k-chunks
    constexpr int PT = (BN * 16) / 512;  // gload_lds issues per thread per chunk
    constexpr int SLAB = BN * 128;       // shorts per buffer
    constexpr int NA = AFP32 ? 4 : 0;    // A global loads per thread per chunk
    static_assert((BN * 16) % 512 == 0, "staging divisibility");
    static_assert(C >= 3, "peel structure needs >=3 chunks");
    __shared__ short Bs[2 * SLAB];
    int tid = threadIdx.x;
    int wave = tid >> 6, lane = tid & 63;
    int quad = lane >> 4, l16 = lane & 15;
    int colBase = blockIdx.y * BN;
    int r0 = blockIdx.x * 128 + wave * 16 + l16;
    int r0c = min(r0, M - 1);
    const short* Bbase = Bg + (size_t)blockIdx.y * (C * SLAB);

    f32x4 acc[NT];
#pragma unroll
    for (int n = 0; n < NT; ++n) acc[n] = (f32x4){0.f, 0.f, 0.f, 0.f};

    auto stageB = [&](int buf, int ck) {
        const short* src = Bbase + (size_t)ck * SLAB;
        short* db = Bs + buf * SLAB;
#pragma unroll
        for (int u = 0; u < PT; ++u) {
            int base = u * 512 + wave * 64;                 // wave-uniform chunk base
            gl16(src + (size_t)(base + lane) * 8, db + (size_t)base * 8);
        }
    };

    short8 aPre[AFP32 ? 2 : (2 * C)];
    short8 aCur[2];
    f32x4 fN[2][4];   // fp32 A double-buffer (2 chunks in flight)
    const float* Af = (const float*)A0v + (size_t)r0c * (size_t)KREAL;

    auto ldA32 = [&](int slot, int ck) {
#pragma unroll
        for (int s = 0; s < 2; ++s) {
            int kg = ck * 64 + s * 32 + quad * 8;
            f32x4 f0 = {0.f, 0.f, 0.f, 0.f}, f1 = {0.f, 0.f, 0.f, 0.f};
            if (kg < KREAL) f0 = *(const f32x4*)(Af + kg);
            if (kg + 4 < KREAL) f1 = *(const f32x4*)(Af + kg + 4);
            fN[slot][s * 2] = f0;
            fN[slot][s * 2 + 1] = f1;
        }
    };
    auto cvtA = [&](int slot) {
#pragma unroll
        for (int s = 0; s < 2; ++s) {
            short8 a;
#pragma unroll
            for (int j = 0; j < 4; ++j) {
                a[j] = (short)f2bf(fN[slot][s * 2][j]);
                a[j + 4] = (short)f2bf(fN[slot][s * 2 + 1][j]);
            }
            aCur[s] = a;
        }
    };
    auto compute = [&](int ck) {
        const short* bb = Bs + (ck & 1) * SLAB;
#pragma unroll
        for (int s = 0; s < 2; ++s) {
            short8 a;
            if constexpr (AFP32) a = aCur[s];
            else                 a = aPre[ck * 2 + s];
#pragma unroll
            for (int n = 0; n < NT; ++n) {
                int r = n * 16 + l16;
                int ch = (s * 4 + quad) ^ (r & 7);
                short8 bh = *(const short8*)(bb + r * 128 + ch * 8);
                short8 bl = *(const short8*)(bb + r * 128 + (8 + ch) * 8);
                acc[n] = __builtin_amdgcn_mfma_f32_16x16x32_bf16(a, bh, acc[n], 0, 0, 0);
                acc[n] = __builtin_amdgcn_mfma_f32_16x16x32_bf16(a, bl, acc[n], 0, 0, 0);
            }
        }
    };

    // ---- prologue: stage(0) first, then A(0), A(1) (so vmcnt(NA) covers stage0+A0) ----
    if constexpr (!AFP32) {
        const short* A0 = (const short*)A0v;
#pragma unroll
        for (int c = 0; c < C; ++c) {
            const bool seg = (c * 64 >= KS0);
            const short* ap = seg ? A1 : A0;
            const int w = seg ? (KPAD - KS0) : KS0;
            const int col = c * 64 - (seg ? KS0 : 0);
#pragma unroll
            for (int s = 0; s < 2; ++s)
                aPre[c * 2 + s] =
                    *(const short8*)(ap + (size_t)r0c * w + col + s * 32 + quad * 8);
        }
    }
    stageB(0, 0);
    if constexpr (AFP32) { ldA32(0, 0); ldA32(1, 1); }

    // ---- main loop: wait(own stage ck) -> barrier -> stage(ck+1) -> compute(ck) ----
#pragma unroll
    for (int ck = 0; ck <= C - 2; ++ck) {
        asm volatile("s_waitcnt vmcnt(%0)" ::"n"(NA) : "memory");
        __builtin_amdgcn_s_barrier();
        __builtin_amdgcn_sched_barrier(0);
        stageB((ck + 1) & 1, ck + 1);
        if constexpr (AFP32) {
            cvtA(ck & 1);
            if (ck + 2 < C) ldA32(ck & 1, ck + 2);
        }
        compute(ck);
    }
    {   // ck = C-1: nothing issued after stage(C-1) -> full drain (only one in the loop)
        asm volatile("s_waitcnt vmcnt(0)" ::: "memory");
        __builtin_amdgcn_s_barrier();
        __builtin_amdgcn_sched_barrier(0);
        if constexpr (AFP32) cvtA((C - 1) & 1);
        compute(C - 1);
    }

    // ---- epilogue: C-layout col=lane&15, row=quad*4+reg ----
    int gr0 = blockIdx.x * 128 + wave * 16 + quad * 4;
#pragma unroll
    for (int n = 0; n < NT; ++n) {
        int gc = colBase + n * 16 + l16;
        if (gc >= N) continue;
        float b = bias ? bias[gc] : 0.f;
#pragma unroll
        for (int r = 0; r < 4; ++r) {
            int gr = gr0 + r;
            if (gr < M) {
                float v = acc[n][r] + b;
                if (RELU) v = fmaxf(v, 0.f);
                if constexpr (PQ) {
                    if (gc < splitN) CH[(size_t)gr * ldc + gc] = (short)f2bf(v);
                    else             F0[(size_t)gr * (N - splitN) + (gc - splitN)] = v;
                } else {
                    if (CH) CH[(size_t)gr * ldc + gc] = (short)f2bf(v);
                    if (F0) {
                        if (gc < splitN) F0[(size_t)gr * splitN + gc] = v;
                        else             F1[(size_t)gr * (N - splitN) + (gc - splitN)] = v;
                    }
                }
            }
        }
    }
}

// ---------------- fused layer-3 aggregation + bias + residual + log_softmax ----------------
// pH: bf16 [NN][64] (cols 0-39 valid, rows 128B-aligned); q: fp32 [NN][40]
// 4-deep unrolled gather for MLP.
__global__ __launch_bounds__(256) void k_final(
    const short* __restrict__ pH, const float* __restrict__ q,
    const int* __restrict__ offs, const int* __restrict__ ssrc,
    const float* __restrict__ bl3, float* __restrict__ out) {
    int wid = (blockIdx.x * 256 + threadIdx.x) >> 6;
    int lane = threadIdx.x & 63;
    if (wid >= NN) return;
    bool act = lane < NCLS;
    int beg = offs[wid], end = offs[wid + 1];
    float a0 = 0.f, a1 = 0.f, a2 = 0.f, a3 = 0.f;
    int i = beg;
    for (; i + 3 < end; i += 4) {
        int s0 = ssrc[i], s1 = ssrc[i + 1], s2 = ssrc[i + 2], s3 = ssrc[i + 3];
        if (act) {
            a0 += bf2f((unsigned short)pH[(size_t)s0 * 64 + lane]);
            a1 += bf2f((unsigned short)pH[(size_t)s1 * 64 + lane]);
            a2 += bf2f((unsigned short)pH[(size_t)s2 * 64 + lane]);
            a3 += bf2f((unsigned short)pH[(size_t)s3 * 64 + lane]);
        }
    }
    for (; i < end; ++i) {
        int s0 = ssrc[i];
        if (act) a0 += bf2f((unsigned short)pH[(size_t)s0 * 64 + lane]);
    }
    float inv = 1.f / fmaxf((float)(end - beg), 1.f);
    float v = act ? ((a0 + a1) + (a2 + a3)) * inv + bl3[lane] + q[(size_t)wid * NCLS + lane]
                  : -INFINITY;
    float m = v;
#pragma unroll
    for (int off = 32; off > 0; off >>= 1) m = fmaxf(m, __shfl_xor(m, off));
    float e = act ? expf(v - m) : 0.f;
    float s = e;
#pragma unroll
    for (int off = 32; off > 0; off >>= 1) s += __shfl_xor(s, off);
    float ls = logf(s);
    if (act) out[(size_t)wid * NCLS + lane] = v - m - ls;
}

extern "C" void kernel_launch(void* const* d_in, const int* in_sizes, int n_in,
                              void* d_out, int out_size, void* d_ws, size_t ws_size,
                              hipStream_t stream) {
    const float* x    = (const float*)d_in[0];
    const int*   ei   = (const int*)d_in[1];
    const int*   esrc = ei;        // row 0: src
    const int*   edst = ei + NE;   // row 1: dst
    const float* W_map = (const float*)d_in[2];
    const float* b_map = (const float*)d_in[3];
    const float* Wl1   = (const float*)d_in[4];
    const float* bl1   = (const float*)d_in[5];
    const float* Wr1   = (const float*)d_in[6];
    const float* Wl2   = (const float*)d_in[7];
    const float* bl2   = (const float*)d_in[8];
    const float* Wr2   = (const float*)d_in[9];
    const float* Wl3   = (const float*)d_in[10];
    const float* bl3   = (const float*)d_in[11];
    const float* Wr3   = (const float*)d_in[12];
    float* out = (float*)d_out;

    char* ws = (char*)d_ws;
    short* h0H = (short*)ws; ws += (size_t)NN * 128 * 2;
    short* m0H = (short*)ws; ws += (size_t)NN * 128 * 2;
    short* h1H = (short*)ws; ws += (size_t)NN * 128 * 2;
    short* m1H = (short*)ws; ws += (size_t)NN * 128 * 2;
    short* h2H = (short*)ws; ws += (size_t)NN * 256 * 2;
    short* pH  = (short*)ws; ws += (size_t)NN * 64 * 2;   // bf16, rows padded to 64
    float* q   = (float*)ws; ws += (size_t)NN * NCLS * 4;
    short* wt  = (short*)ws; ws += (size_t)376832 * 2;
    int* deg    = (int*)ws;  ws += (size_t)NN * 4;
    int* offs   = (int*)ws;  ws += (size_t)(NN + 2) * 4;
    int* cursor = (int*)ws;  ws += (size_t)NN * 4;
    int* ssrc   = (int*)ws;  ws += (size_t)NE * 4;
    int* bsum   = (int*)ws;  ws += (size_t)256 * 4;
    int* bpre   = (int*)ws;  ws += (size_t)256 * 4;

    // blocked pre-swizzled weight buffers: [yb][ck64][BN][128], BN=128 (b3w: 96)
    short* m_w  = wt + 0;       // 1yb * 8ck * 128 * 128 = 131072
    short* b1w  = wt + 131072;  // 1yb * 4ck * 128 * 128 = 65536
    short* b2w  = wt + 196608;  // 2yb * 4ck * 128 * 128 = 131072
    short* b3w  = wt + 327680;  // 1yb * 4ck *  96 * 128 = 49152  (total 376832)

    // --- weight split/transpose (tiny) ---
    (void)hipMemsetAsync(b3w, 0, (size_t)49152 * 2, stream);  // zero pad rows 80-95
    k_wsplit<<<(128 * 512 + 255) / 256, 256, 0, stream>>>(W_map, m_w, FIN, 128, 512, 128, 0, 0, 9);
    k_wsplit<<<(128 * 128 + 255) / 256, 256, 0, stream>>>(Wr1, b1w, 128, 128, 256, 128, 0, 0, 7);
    k_wsplit<<<(128 * 128 + 255) / 256, 256, 0, stream>>>(Wl1, b1w, 128, 128, 256, 128, 128, 0, 7);
    k_wsplit<<<(256 * 128 + 255) / 256, 256, 0, stream>>>(Wr2, b2w, 128, 256, 256, 128, 0, 0, 7);
    k_wsplit<<<(256 * 128 + 255) / 256, 256, 0, stream>>>(Wl2, b2w, 128, 256, 256, 128, 128, 0, 7);
    k_wsplit<<<(40 * 256 + 255) / 256, 256, 0, stream>>>(Wl3, b3w, 256, 40, 256, 96, 0, 0, 8);
    k_wsplit<<<(40 * 256 + 255) / 256, 256, 0, stream>>>(Wr3, b3w, 256, 40, 256, 96, 0, 40, 8);

    // --- CSR bucketing of edges by dst (two-level scan) ---
    (void)hipMemsetAsync(deg, 0, (size_t)NN * 4, stream);
    k_count<<<(NE + 255) / 256, 256, 0, stream>>>(edst, deg);
    k_scan1<<<NB, 256, 0, stream>>>(deg, offs, bsum);
    k_scan2<<<1, 256, 0, stream>>>(bsum, bpre, offs);
    k_scan3<<<NB, 256, 0, stream>>>(offs, bpre, cursor);
    k_scatter<<<(NE + 255) / 256, 256, 0, stream>>>(esrc, edst, cursor, ssrc);

    const int g128 = (NN + 127) / 128;  // 391
    const int aggBlocks = (NN * 64) / 256;

    // h0 = x @ W_map + b_map -> h0H [NN][128] bf16
    k_mm8<128, 512, 512, FIN, true, false, false><<<dim3(g128, 1), 512, 0, stream>>>(
        (const void*)x, nullptr, m_w, b_map,
        h0H, 128, nullptr, nullptr, 0, NN, 128);

    // mean(h0) -> m0H
    k_aggb<<<aggBlocks, 256, 0, stream>>>(h0H, offs, ssrc, m0H);

    // h1 = relu([h0|mean] @ [Wr1;Wl1] + bl1) -> h1H
    k_mm8<128, 256, 128, 256, false, true, false><<<dim3(g128, 1), 512, 0, stream>>>(
        (const void*)h0H, m0H, b1w, bl1,
        h1H, 128, nullptr, nullptr, 0, NN, 128);

    // mean(h1) -> m1H
    k_aggb<<<aggBlocks, 256, 0, stream>>>(h1H, offs, ssrc, m1H);

    // h2 = relu([h1|mean] @ [Wr2;Wl2] + bl2) -> h2H [NN][256]
    k_mm8<128, 256, 128, 256, false, true, false><<<dim3(g128, 2), 512, 0, stream>>>(
        (const void*)h1H, m1H, b2w, bl2,
        h2H, 256, nullptr, nullptr, 0, NN, 256);

    // [p|q] = h2 @ [Wl3|Wr3] (BN padded to 96): cols 0-39 -> pH (bf16, ldc=64), 40-79 -> q
    k_mm8<96, 256, 256, 256, false, false, true><<<dim3(g128, 1), 512, 0, stream>>>(
        (const void*)h2H, nullptr, b3w, nullptr,
        pH, 64, q, nullptr, NCLS, NN, 80);

    // fused: logits = mean_agg(pH) + bl3 + q; log_softmax -> out
    k_final<<<aggBlocks, 256, 0, stream>>>(pH, q, offs, ssrc, bl3, out);
}